// Round 1
// baseline (268.849 us; speedup 1.0000x reference)
//
#include <hip/hip_runtime.h>
#include <math.h>

#define Bdim 4
#define Sdim 1024
#define Ddim 384
#define NUM_ITEMS 16384
#define NUM_CLUSTERS 256
#define MAX_CLUSTER_SIZE 128
#define NEG_INF_F (-1e9f)
#define NTOK (Bdim * Sdim)

// One block per token. 256 threads (4 waves).
__global__ __launch_bounds__(256) void hs_token_kernel(
    const float* __restrict__ hidden,        // [NTOK, D]
    const float* __restrict__ item_emb,      // [NUM_ITEMS, D]
    const float* __restrict__ cluster_emb,   // [NUM_CLUSTERS, D]
    const float* __restrict__ item_mask,     // [NTOK]
    const int*   __restrict__ targets,       // [NTOK]
    const int*   __restrict__ cluster_assign,// [NUM_ITEMS]
    const int*   __restrict__ cluster_idx,   // [NUM_CLUSTERS, MAX_CLUSTER_SIZE]
    const int*   __restrict__ in_cluster_id, // [NUM_ITEMS]
    float* __restrict__ ws)                  // [5 * NTOK]
{
    __shared__ float h[Ddim];
    __shared__ float clog[NUM_CLUSTERS];
    __shared__ float memb[MAX_CLUSTER_SIZE];
    __shared__ float red[256];
    __shared__ int   redi[256];

    const int t   = blockIdx.x;
    const int tid = threadIdx.x;

    // ---- stage hidden row into LDS (float4) ----
    const float4* h4g = reinterpret_cast<const float4*>(hidden + (size_t)t * Ddim);
    float4* h4s = reinterpret_cast<float4*>(h);
    if (tid < Ddim / 4) h4s[tid] = h4g[tid];
    __syncthreads();

    // ---- cluster logits: thread c = tid computes dot(h, CE[c]) ----
    {
        const float4* ce = reinterpret_cast<const float4*>(cluster_emb + (size_t)tid * Ddim);
        float acc = 0.f;
        #pragma unroll 8
        for (int k = 0; k < Ddim / 4; ++k) {
            float4 a = ce[k];
            float4 b = h4s[k];
            acc += a.x * b.x + a.y * b.y + a.z * b.z + a.w * b.w;
        }
        clog[tid] = acc;
    }
    __syncthreads();

    // ---- argmax + max (first-index tiebreak, matches jnp.argmax) ----
    red[tid]  = clog[tid];
    redi[tid] = tid;
    __syncthreads();
    for (int s2 = 128; s2 > 0; s2 >>= 1) {
        if (tid < s2) {
            float v2 = red[tid + s2]; int i2 = redi[tid + s2];
            if (v2 > red[tid] || (v2 == red[tid] && i2 < redi[tid])) {
                red[tid] = v2; redi[tid] = i2;
            }
        }
        __syncthreads();
    }
    const float cmax   = red[0];
    const int   cargmx = redi[0];
    __syncthreads();

    // ---- sum exp(clog - cmax) ----
    red[tid] = expf(clog[tid] - cmax);
    __syncthreads();
    for (int s2 = 128; s2 > 0; s2 >>= 1) {
        if (tid < s2) red[tid] += red[tid + s2];
        __syncthreads();
    }
    const float csum = red[0];
    __syncthreads();

    // ---- target info (uniform per block; redundant loads are cached) ----
    const int tgt  = targets[t];
    const int tc   = cluster_assign[tgt];
    const int tpos = in_cluster_id[tgt];
    const float tlp_cluster = clog[tc] - cmax - logf(csum);

    // ---- member logits: thread m < 128 handles slot m ----
    if (tid < MAX_CLUSTER_SIZE) {
        float mlogit = NEG_INF_F;
        const int id = cluster_idx[tc * MAX_CLUSTER_SIZE + tid];
        if (id >= 0) {
            const float4* ie = reinterpret_cast<const float4*>(item_emb + (size_t)id * Ddim);
            float acc = 0.f;
            #pragma unroll 8
            for (int k = 0; k < Ddim / 4; ++k) {
                float4 a = ie[k];
                float4 b = h4s[k];
                acc += a.x * b.x + a.y * b.y + a.z * b.z + a.w * b.w;
            }
            mlogit = acc;
        }
        memb[tid] = mlogit;
    }
    __syncthreads();

    // ---- member max ----
    red[tid] = (tid < MAX_CLUSTER_SIZE) ? memb[tid] : NEG_INF_F;
    __syncthreads();
    for (int s2 = 128; s2 > 0; s2 >>= 1) {
        if (tid < s2) red[tid] = fmaxf(red[tid], red[tid + s2]);
        __syncthreads();
    }
    const float mmax = red[0];
    __syncthreads();

    // ---- member sum exp ----
    red[tid] = (tid < MAX_CLUSTER_SIZE) ? expf(memb[tid] - mmax) : 0.f;
    __syncthreads();
    for (int s2 = 128; s2 > 0; s2 >>= 1) {
        if (tid < s2) red[tid] += red[tid + s2];
        __syncthreads();
    }
    const float msum = red[0];

    if (tid == 0) {
        const float tlp_item = memb[tpos] - mmax - logf(msum);
        const float m    = item_mask[t];
        const float loss = -(tlp_cluster + tlp_item);
        ws[t]            = loss * m;
        ws[NTOK + t]     = m;
        ws[2 * NTOK + t] = tlp_cluster;
        ws[3 * NTOK + t] = tlp_item;
        ws[4 * NTOK + t] = (cargmx == tc) ? 1.f : 0.f;
    }
}

// Single block, deterministic fixed-order reduction of the 5 per-token arrays.
__global__ __launch_bounds__(256) void hs_final_kernel(
    const float* __restrict__ ws, float* __restrict__ out)
{
    __shared__ double red[5][256];
    const int tid = threadIdx.x;
    double a0 = 0, a1 = 0, a2 = 0, a3 = 0, a4 = 0;
    for (int i = tid; i < NTOK; i += 256) {
        a0 += (double)ws[i];
        a1 += (double)ws[NTOK + i];
        a2 += (double)ws[2 * NTOK + i];
        a3 += (double)ws[3 * NTOK + i];
        a4 += (double)ws[4 * NTOK + i];
    }
    red[0][tid] = a0; red[1][tid] = a1; red[2][tid] = a2;
    red[3][tid] = a3; red[4][tid] = a4;
    __syncthreads();
    for (int s2 = 128; s2 > 0; s2 >>= 1) {
        if (tid < s2) {
            red[0][tid] += red[0][tid + s2];
            red[1][tid] += red[1][tid + s2];
            red[2][tid] += red[2][tid + s2];
            red[3][tid] += red[3][tid + s2];
            red[4][tid] += red[4][tid + s2];
        }
        __syncthreads();
    }
    if (tid == 0) {
        const double total_loss = red[0][0] / (red[1][0] + 1e-8);
        out[0] = (float)total_loss;
        out[1] = (float)(-red[2][0] / (double)NTOK);
        out[2] = (float)(-red[3][0] / (double)NTOK);
        out[3] = (float)(red[4][0] / (double)NTOK);
    }
}

extern "C" void kernel_launch(void* const* d_in, const int* in_sizes, int n_in,
                              void* d_out, int out_size, void* d_ws, size_t ws_size,
                              hipStream_t stream) {
    const float* hidden         = (const float*)d_in[0];
    const float* item_emb       = (const float*)d_in[1];
    const float* cluster_emb    = (const float*)d_in[2];
    const float* item_mask      = (const float*)d_in[3];
    const int*   targets        = (const int*)d_in[4];
    const int*   cluster_assign = (const int*)d_in[5];
    const int*   cluster_idx    = (const int*)d_in[6];
    const int*   in_cluster_id  = (const int*)d_in[7];

    float* out = (float*)d_out;
    float* ws  = (float*)d_ws;

    const size_t dummy_elems = (size_t)Bdim * Sdim * NUM_ITEMS; // 67,108,864

    // dummy_logits is all zeros in the reference -> memset (graph-capture safe)
    hipMemsetAsync(d_out, 0, dummy_elems * sizeof(float), stream);

    hs_token_kernel<<<NTOK, 256, 0, stream>>>(
        hidden, item_emb, cluster_emb, item_mask, targets,
        cluster_assign, cluster_idx, in_cluster_id, ws);

    hs_final_kernel<<<1, 256, 0, stream>>>(ws, out + dummy_elems);
}

// Round 3
// 248.388 us; speedup vs baseline: 1.0824x; 1.0824x over previous
//
#include <hip/hip_runtime.h>
#include <math.h>

#define Bdim 4
#define Sdim 1024
#define Ddim 384
#define NUM_ITEMS 16384
#define NUM_CLUSTERS 256
#define MAX_CLUSTER_SIZE 128
#define NEG_INF_F (-1e9f)
#define NTOK (Bdim * Sdim)

#define TT 8                      // tokens per compute block
#define NCB (NTOK / TT)           // 512 compute blocks
#define NFB 512                   // fill blocks
#define FILL_F4 32768             // float4s per fill block (512 KB)

typedef float vfloat4 __attribute__((ext_vector_type(4)));

// Even blockIdx -> compute block (8 tokens). Odd blockIdx -> zero-fill block.
__global__ __launch_bounds__(256) void hs_fused_kernel(
    const float* __restrict__ hidden,        // [NTOK, D]
    const float* __restrict__ item_emb,      // [NUM_ITEMS, D]
    const float* __restrict__ cluster_emb,   // [NUM_CLUSTERS, D]
    const float* __restrict__ item_mask,     // [NTOK]
    const int*   __restrict__ targets,       // [NTOK]
    const int*   __restrict__ cluster_assign,// [NUM_ITEMS]
    const int*   __restrict__ cluster_idx,   // [NUM_CLUSTERS, M]
    const int*   __restrict__ in_cluster_id, // [NUM_ITEMS]
    float* __restrict__ dummy_out,           // [NTOK * NUM_ITEMS] -> zeros
    float* __restrict__ ws)                  // [5 * NTOK]
{
    const int bid = blockIdx.x;
    const int tid = threadIdx.x;

    if (bid & 1) {
        // ---------------- fill block: zero 512 KB of dummy_out ----------------
        const int fid = bid >> 1;
        vfloat4 z = (vfloat4)0.f;
        vfloat4* o4 = reinterpret_cast<vfloat4*>(dummy_out)
                      + (size_t)fid * FILL_F4 + tid;
        #pragma unroll 4
        for (int i = 0; i < FILL_F4 / 256; ++i) {
            __builtin_nontemporal_store(z, o4 + (size_t)i * 256);
        }
        return;
    }

    // ---------------- compute block: tokens [t0, t0+8) ----------------
    const int cb   = bid >> 1;
    const int t0   = cb * TT;
    const int lane = tid & 63;
    const int wid  = tid >> 6;

    __shared__ float h_lds[TT][Ddim];                 // 12 KB
    __shared__ float clog[TT][NUM_CLUSTERS];          // 8 KB
    __shared__ float mlog[TT][MAX_CLUSTER_SIZE];      // 4 KB
    __shared__ int   mids[TT][MAX_CLUSTER_SIZE];      // 4 KB
    __shared__ int   tci[TT], tposi[TT], cargm[TT];
    __shared__ float tmaskv[TT], tlpc[TT];

    if (tid < TT) {
        const int tgt = targets[t0 + tid];
        tci[tid]    = cluster_assign[tgt];
        tposi[tid]  = in_cluster_id[tgt];
        tmaskv[tid] = item_mask[t0 + tid];
    }
    __syncthreads();

    // stage h tile (coalesced float4) + member ids + init mlog
    {
        const float4* hg = reinterpret_cast<const float4*>(hidden + (size_t)t0 * Ddim);
        float4* hs = reinterpret_cast<float4*>(&h_lds[0][0]);
        #pragma unroll
        for (int i = 0; i < (TT * Ddim / 4) / 256; ++i)
            hs[i * 256 + tid] = hg[i * 256 + tid];
        #pragma unroll
        for (int i = 0; i < (TT * MAX_CLUSTER_SIZE) / 256; ++i) {
            const int idx = i * 256 + tid;
            const int t = idx >> 7, s = idx & 127;
            mids[t][s] = cluster_idx[tci[t] * MAX_CLUSTER_SIZE + s];
            mlog[t][s] = NEG_INF_F;
        }
    }
    __syncthreads();

    // per-lane h fragments for all 8 tokens: hf[t][j] = h[t][j*64 + lane]
    float hf[TT][6];
    #pragma unroll
    for (int t = 0; t < TT; ++t)
        #pragma unroll
        for (int j = 0; j < 6; ++j)
            hf[t][j] = h_lds[t][j * 64 + lane];

    // ---- cluster logits: wave w computes clusters [w*64, w*64+64) ----
    #pragma unroll 2
    for (int cc = 0; cc < 64; ++cc) {
        const int c = wid * 64 + cc;
        const float* ce = cluster_emb + (size_t)c * Ddim;
        float cef[6];
        #pragma unroll
        for (int j = 0; j < 6; ++j) cef[j] = ce[j * 64 + lane];   // coalesced
        float acc[TT];
        #pragma unroll
        for (int t = 0; t < TT; ++t) acc[t] = 0.f;
        #pragma unroll
        for (int j = 0; j < 6; ++j)
            #pragma unroll
            for (int t = 0; t < TT; ++t)
                acc[t] += cef[j] * hf[t][j];
        #pragma unroll
        for (int t = 0; t < TT; ++t) {
            float v = acc[t];
            #pragma unroll
            for (int m = 32; m > 0; m >>= 1) v += __shfl_xor(v, m);
            if (lane == 0) clog[t][c] = v;
        }
    }
    __syncthreads();

    // ---- cluster softmax + argmax (first-index tiebreak): wave w -> tokens w, w+4 ----
    #pragma unroll
    for (int q = 0; q < 2; ++q) {
        const int t = wid + q * 4;
        const float v0 = clog[t][lane];
        const float v1 = clog[t][lane + 64];
        const float v2 = clog[t][lane + 128];
        const float v3 = clog[t][lane + 192];
        float bv = v0; int bi = lane;
        if (v1 > bv) { bv = v1; bi = lane + 64;  }
        if (v2 > bv) { bv = v2; bi = lane + 128; }
        if (v3 > bv) { bv = v3; bi = lane + 192; }
        #pragma unroll
        for (int m = 32; m > 0; m >>= 1) {
            const float ov = __shfl_xor(bv, m);
            const int   oi = __shfl_xor(bi, m);
            if (ov > bv || (ov == bv && oi < bi)) { bv = ov; bi = oi; }
        }
        float e = expf(v0 - bv) + expf(v1 - bv) + expf(v2 - bv) + expf(v3 - bv);
        #pragma unroll
        for (int m = 32; m > 0; m >>= 1) e += __shfl_xor(e, m);
        const float lse = bv + logf(e);
        if (lane == 0) {
            tlpc[t]  = clog[t][tci[t]] - lse;
            cargm[t] = bi;
        }
    }
    __syncthreads();

    // ---- member logits: wave w -> tokens w, w+4; wave-cooperative dot per slot ----
    #pragma unroll
    for (int q = 0; q < 2; ++q) {
        const int t = wid + q * 4;
        float hm[6];
        #pragma unroll
        for (int j = 0; j < 6; ++j) hm[j] = h_lds[t][j * 64 + lane];
        #pragma unroll 1
        for (int s = 0; s < MAX_CLUSTER_SIZE; ++s) {
            const int id = mids[t][s];            // uniform broadcast
            if (id >= 0) {
                const float* ir = item_emb + (size_t)id * Ddim;
                float p = 0.f;
                #pragma unroll
                for (int j = 0; j < 6; ++j) p += ir[j * 64 + lane] * hm[j]; // coalesced
                #pragma unroll
                for (int m = 32; m > 0; m >>= 1) p += __shfl_xor(p, m);
                if (lane == 0) mlog[t][s] = p;
            }
        }
    }
    __syncthreads();

    // ---- member softmax + per-token outputs ----
    #pragma unroll
    for (int q = 0; q < 2; ++q) {
        const int t = wid + q * 4;
        const float w0 = mlog[t][lane];
        const float w1 = mlog[t][lane + 64];
        float mx = fmaxf(w0, w1);
        #pragma unroll
        for (int m = 32; m > 0; m >>= 1) mx = fmaxf(mx, __shfl_xor(mx, m));
        float e = expf(w0 - mx) + expf(w1 - mx);   // exp(NEG_INF - mx) == 0
        #pragma unroll
        for (int m = 32; m > 0; m >>= 1) e += __shfl_xor(e, m);
        const float lse = mx + logf(e);
        if (lane == 0) {
            const float tlpi  = mlog[t][tposi[t]] - lse;
            const float tc_lp = tlpc[t];
            const float msk   = tmaskv[t];
            const int   gt    = t0 + t;
            ws[gt]            = -(tc_lp + tlpi) * msk;
            ws[NTOK + gt]     = msk;
            ws[2 * NTOK + gt] = tc_lp;
            ws[3 * NTOK + gt] = tlpi;
            ws[4 * NTOK + gt] = (cargm[t] == tci[t]) ? 1.f : 0.f;
        }
    }
}

// Single block, deterministic fixed-order reduction of the 5 per-token arrays.
__global__ __launch_bounds__(256) void hs_final_kernel(
    const float* __restrict__ ws, float* __restrict__ out)
{
    __shared__ double red[5][256];
    const int tid = threadIdx.x;
    double a0 = 0, a1 = 0, a2 = 0, a3 = 0, a4 = 0;
    for (int i = tid; i < NTOK; i += 256) {
        a0 += (double)ws[i];
        a1 += (double)ws[NTOK + i];
        a2 += (double)ws[2 * NTOK + i];
        a3 += (double)ws[3 * NTOK + i];
        a4 += (double)ws[4 * NTOK + i];
    }
    red[0][tid] = a0; red[1][tid] = a1; red[2][tid] = a2;
    red[3][tid] = a3; red[4][tid] = a4;
    __syncthreads();
    for (int s2 = 128; s2 > 0; s2 >>= 1) {
        if (tid < s2) {
            red[0][tid] += red[0][tid + s2];
            red[1][tid] += red[1][tid + s2];
            red[2][tid] += red[2][tid + s2];
            red[3][tid] += red[3][tid + s2];
            red[4][tid] += red[4][tid + s2];
        }
        __syncthreads();
    }
    if (tid == 0) {
        out[0] = (float)(red[0][0] / (red[1][0] + 1e-8));
        out[1] = (float)(-red[2][0] / (double)NTOK);
        out[2] = (float)(-red[3][0] / (double)NTOK);
        out[3] = (float)(red[4][0] / (double)NTOK);
    }
}

extern "C" void kernel_launch(void* const* d_in, const int* in_sizes, int n_in,
                              void* d_out, int out_size, void* d_ws, size_t ws_size,
                              hipStream_t stream) {
    const float* hidden         = (const float*)d_in[0];
    const float* item_emb       = (const float*)d_in[1];
    const float* cluster_emb    = (const float*)d_in[2];
    const float* item_mask      = (const float*)d_in[3];
    const int*   targets        = (const int*)d_in[4];
    const int*   cluster_assign = (const int*)d_in[5];
    const int*   cluster_idx    = (const int*)d_in[6];
    const int*   in_cluster_id  = (const int*)d_in[7];

    float* out = (float*)d_out;
    float* ws  = (float*)d_ws;

    const size_t dummy_elems = (size_t)NTOK * NUM_ITEMS; // 67,108,864 zeros

    hs_fused_kernel<<<NCB + NFB, 256, 0, stream>>>(
        hidden, item_emb, cluster_emb, item_mask, targets,
        cluster_assign, cluster_idx, in_cluster_id, out, ws);

    hs_final_kernel<<<1, 256, 0, stream>>>(ws, out + dummy_elems);
}

// Round 4
// 138.445 us; speedup vs baseline: 1.9419x; 1.7941x over previous
//
#include <hip/hip_runtime.h>
#include <math.h>

#define Ddim 384
#define D4 96                      // Ddim/4
#define NUM_ITEMS 16384
#define NUM_CLUSTERS 256
#define MCS 128                    // MAX_CLUSTER_SIZE
#define NEG_INF_F (-1e9f)
#define NTOK 4096
#define TT 4                       // tokens per compute block (1 per wave)
#define NCB 1024                   // compute blocks
#define NFB 512                    // fill blocks
#define FILL_F4 32768              // float4s per fill block (512 KB)

typedef float vfloat4 __attribute__((ext_vector_type(4)));

__device__ __forceinline__ float dot4(const float4& a, const float4& b) {
    return a.x * b.x + a.y * b.y + a.z * b.z + a.w * b.w;
}

// bid % 3 == 0 -> fill block (512 of 1536); else compute block (1024).
__global__ __launch_bounds__(256) void hs_fused(
    const float* __restrict__ hidden,        // [NTOK, D]
    const float* __restrict__ item_emb,      // [NUM_ITEMS, D]
    const float* __restrict__ cluster_emb,   // [NUM_CLUSTERS, D]
    const float* __restrict__ item_mask,     // [NTOK]
    const int*   __restrict__ targets,       // [NTOK]
    const int*   __restrict__ cluster_assign,// [NUM_ITEMS]
    const int*   __restrict__ cluster_idx,   // [NUM_CLUSTERS, MCS]
    const int*   __restrict__ in_cluster_id, // [NUM_ITEMS]
    float* __restrict__ dummy_out,           // [NTOK * NUM_ITEMS] -> zeros
    float* __restrict__ ws)                  // [5 * NTOK]
{
    const int bid = blockIdx.x;
    const int tid = threadIdx.x;

    if (bid % 3 == 0) {
        // ------------- fill block: zero 512 KB of dummy_out -------------
        const int fid = bid / 3;
        vfloat4 z = (vfloat4)0.f;
        vfloat4* o4 = reinterpret_cast<vfloat4*>(dummy_out)
                      + (size_t)fid * FILL_F4 + tid;
        #pragma unroll 8
        for (int i = 0; i < FILL_F4 / 256; ++i)
            __builtin_nontemporal_store(z, o4 + (size_t)i * 256);
        return;
    }

    // ------------- compute block: tokens [t0, t0+4), one per wave -------------
    const int cb   = 2 * (bid / 3) + (bid % 3) - 1;   // 0..1023
    const int t0   = cb * TT;
    const int lane = tid & 63;
    const int wid  = tid >> 6;
    const int g    = lane >> 3;    // row group 0..7
    const int r    = lane & 7;     // lane within group

    __shared__ float4 h4[TT][D4];                 // 6 KB
    __shared__ float  clog[TT][NUM_CLUSTERS];     // 4 KB
    __shared__ float  mlog[TT][MCS];              // 2 KB

    // ---- stage h tile (coalesced float4) ----
    {
        const float4* hg = reinterpret_cast<const float4*>(hidden) + (size_t)t0 * D4;
        float4* hs = &h4[0][0];
        for (int i = tid; i < TT * D4; i += 256) hs[i] = hg[i];
    }
    __syncthreads();   // the ONLY barrier; waves are independent below

    const int   t    = wid;          // token within tile
    const int   gt   = t0 + wid;     // global token
    const int   tgt  = targets[gt];
    const int   tc   = cluster_assign[tgt];
    const int   tpos = in_cluster_id[tgt];
    const float msk  = item_mask[gt];

    // per-lane h fragment: covers float4 indices {r, r+8, ..., r+88}
    float4 hm[12];
    #pragma unroll
    for (int i = 0; i < 12; ++i) hm[i] = h4[t][i * 8 + r];

    // ---- cluster logits: 8 clusters per iteration (group g -> cluster it*8+g) ----
    #pragma unroll 2
    for (int it = 0; it < 32; ++it) {
        const int c = it * 8 + g;
        const float4* ce = reinterpret_cast<const float4*>(cluster_emb) + (size_t)c * D4;
        float p = 0.f;
        #pragma unroll
        for (int i = 0; i < 12; ++i) p += dot4(ce[i * 8 + r], hm[i]);
        p += __shfl_xor(p, 1); p += __shfl_xor(p, 2); p += __shfl_xor(p, 4);
        if (r == 0) clog[t][c] = p;
    }

    // ---- cluster softmax + argmax (first-index tiebreak), wave-local ----
    float tlpc;
    int   cargm;
    {
        const float v0 = clog[t][lane];
        const float v1 = clog[t][lane + 64];
        const float v2 = clog[t][lane + 128];
        const float v3 = clog[t][lane + 192];
        float bv = v0; int bi = lane;
        if (v1 > bv) { bv = v1; bi = lane + 64;  }
        if (v2 > bv) { bv = v2; bi = lane + 128; }
        if (v3 > bv) { bv = v3; bi = lane + 192; }
        #pragma unroll
        for (int m = 32; m > 0; m >>= 1) {
            const float ov = __shfl_xor(bv, m);
            const int   oi = __shfl_xor(bi, m);
            if (ov > bv || (ov == bv && oi < bi)) { bv = ov; bi = oi; }
        }
        float e = expf(v0 - bv) + expf(v1 - bv) + expf(v2 - bv) + expf(v3 - bv);
        #pragma unroll
        for (int m = 32; m > 0; m >>= 1) e += __shfl_xor(e, m);
        const float lse = bv + logf(e);
        tlpc  = clog[t][tc] - lse;
        cargm = bi;
    }

    // ---- member logits: 8 slots per iteration ----
    const int* crow = cluster_idx + (size_t)tc * MCS;
    #pragma unroll 2
    for (int it = 0; it < 16; ++it) {
        const int id = crow[it * 8 + g];          // group-uniform, L1-cached
        float p = 0.f;
        if (id >= 0) {
            const float4* ir = reinterpret_cast<const float4*>(item_emb) + (size_t)id * D4;
            #pragma unroll
            for (int i = 0; i < 12; ++i) p += dot4(ir[i * 8 + r], hm[i]);
        }
        p += __shfl_xor(p, 1); p += __shfl_xor(p, 2); p += __shfl_xor(p, 4);
        if (r == 0) mlog[t][it * 8 + g] = (id >= 0) ? p : NEG_INF_F;
    }

    // ---- member softmax, wave-local ----
    const float w0 = mlog[t][lane];
    const float w1 = mlog[t][lane + 64];
    float mx = fmaxf(w0, w1);
    #pragma unroll
    for (int m = 32; m > 0; m >>= 1) mx = fmaxf(mx, __shfl_xor(mx, m));
    float e2 = expf(w0 - mx) + expf(w1 - mx);     // exp(NEG_INF - mx) == 0
    #pragma unroll
    for (int m = 32; m > 0; m >>= 1) e2 += __shfl_xor(e2, m);
    const float lse2 = mx + logf(e2);
    const float tlpi = mlog[t][tpos] - lse2;

    if (lane == 0) {
        ws[gt]            = -(tlpc + tlpi) * msk;
        ws[NTOK + gt]     = msk;
        ws[2 * NTOK + gt] = tlpc;
        ws[3 * NTOK + gt] = tlpi;
        ws[4 * NTOK + gt] = (cargm == tc) ? 1.f : 0.f;
    }
}

// Single block (1024 threads), deterministic fixed-order reduction.
__global__ __launch_bounds__(1024) void hs_final(
    const float* __restrict__ ws, float* __restrict__ out)
{
    __shared__ double red[5][1024];   // 40 KB
    const int tid = threadIdx.x;
    double a0 = 0, a1 = 0, a2 = 0, a3 = 0, a4 = 0;
    for (int i = tid; i < NTOK; i += 1024) {
        a0 += (double)ws[i];
        a1 += (double)ws[NTOK + i];
        a2 += (double)ws[2 * NTOK + i];
        a3 += (double)ws[3 * NTOK + i];
        a4 += (double)ws[4 * NTOK + i];
    }
    red[0][tid] = a0; red[1][tid] = a1; red[2][tid] = a2;
    red[3][tid] = a3; red[4][tid] = a4;
    __syncthreads();
    for (int s2 = 512; s2 > 0; s2 >>= 1) {
        if (tid < s2) {
            red[0][tid] += red[0][tid + s2];
            red[1][tid] += red[1][tid + s2];
            red[2][tid] += red[2][tid + s2];
            red[3][tid] += red[3][tid + s2];
            red[4][tid] += red[4][tid + s2];
        }
        __syncthreads();
    }
    if (tid == 0) {
        out[0] = (float)(red[0][0] / (red[1][0] + 1e-8));
        out[1] = (float)(-red[2][0] / (double)NTOK);
        out[2] = (float)(-red[3][0] / (double)NTOK);
        out[3] = (float)(red[4][0] / (double)NTOK);
    }
}

extern "C" void kernel_launch(void* const* d_in, const int* in_sizes, int n_in,
                              void* d_out, int out_size, void* d_ws, size_t ws_size,
                              hipStream_t stream) {
    const float* hidden         = (const float*)d_in[0];
    const float* item_emb       = (const float*)d_in[1];
    const float* cluster_emb    = (const float*)d_in[2];
    const float* item_mask      = (const float*)d_in[3];
    const int*   targets        = (const int*)d_in[4];
    const int*   cluster_assign = (const int*)d_in[5];
    const int*   cluster_idx    = (const int*)d_in[6];
    const int*   in_cluster_id  = (const int*)d_in[7];

    float* out = (float*)d_out;
    float* ws  = (float*)d_ws;

    const size_t dummy_elems = (size_t)NTOK * NUM_ITEMS; // 67,108,864 zeros

    hs_fused<<<NCB + NFB, 256, 0, stream>>>(
        hidden, item_emb, cluster_emb, item_mask, targets,
        cluster_assign, cluster_idx, in_cluster_id, out, ws);

    hs_final<<<1, 1024, 0, stream>>>(ws, out + dummy_elems);
}